// Round 2
// baseline (226.534 us; speedup 1.0000x reference)
//
#include <hip/hip_runtime.h>
#include <hip/hip_cooperative_groups.h>
#include <math.h>

namespace cg = cooperative_groups;

#define THREADS 1024   // 16 waves/block, 1 block/CU at grid 256 (coop co-residency exact)
#define NBLOCKS 256
#define CACHE_K 16     // 4M points / (256*1024) = 16 points/thread, all cached in regs

// ---- monotone float <-> uint encoding (order-preserving) ----
__device__ __forceinline__ unsigned enc_f(float f) {
    unsigned b = __float_as_uint(f);
    return (b & 0x80000000u) ? ~b : (b | 0x80000000u);
}
__device__ __forceinline__ float dec_f(unsigned u) {
    unsigned b = (u & 0x80000000u) ? (u ^ 0x80000000u) : ~u;
    return __uint_as_float(b);
}
#define ENC_NEG_INF 0x007FFFFFu   // enc(-inf): identity for max
#define ENC_POS_INF 0xFF800000u   // enc(+inf): identity for min
// word w in a 32-word stat record: [0..7] gmax(max) [8..15] pmin(min) [16..23] zmin(min) [24..31] zmax(max)
__device__ __forceinline__ unsigned ident_w(int w) {
    return (w < 8 || w >= 24) ? ENC_NEG_INF : ENC_POS_INF;
}

// ws layout (unsigned*):
//   [32..33] double acc  | [34] done-counter        (zeroed by block 0 at entry)
//   [64 + blk*32 + w]    per-block stat slots
#define SLOT(base, blk) ((base) + 64 + (blk) * 32)

#define CNT_B(ii, bdst) do { bdst = 0; \
    _Pragma("unroll") for (int j_ = 0; j_ < 8; ++j_) bdst += ((ii) >= roff[j_]); } while (0)

#define FLUSH_LDS(bb, g_, p_, mn_, mx_) do { \
    atomicMax(&s_stats[      (bb)], enc_f(g_));  \
    atomicMin(&s_stats[ 8  + (bb)], enc_f(p_));  \
    atomicMin(&s_stats[16  + (bb)], enc_f(mn_)); \
    atomicMax(&s_stats[24  + (bb)], enc_f(mx_)); } while (0)

__device__ __forceinline__ float point_loss(float p0, float p1, int s, float z, float mu) {
    float m   = fmaxf(p0, p1);
    float lse = m + logf(expf(p0 - m) + expf(p1 - m));
    float lpt = ((s == 0) ? p0 : p1) - lse;
    float pt  = expf(lpt);
    float om  = 1.0f - pt;
    float loss = -lpt * om * om;           // LOSS_WEIGHT=ALPHA=1, GAMMA=2
    float d  = z - mu;
    float cf = (z <= mu) ? 50.0f : 3.125f; // 1/(2*0.1^2), 1/(2*0.4^2)
    float w  = expf(-d * d * cf);
    if (z > mu && d > 0.8f) w = 0.1f;      // d > 2*0.4 -> MIN_VAL
    return loss * w;
}

// Fused single-pass kernel: phase 1 (stats; FULL uniform tiles cache z+seg in regs)
// -> grid sync -> phase 2 (loss; fast tiles read only pred from HBM).
// zc[]/sv[] are touched ONLY in fully-unrolled, branch-free fast-path code so
// mem2reg promotion is guaranteed (R1 regression: scratch demotion -> VGPR=32, 136us).
__global__ __launch_bounds__(THREADS, 4) void k_fused(
        const float* __restrict__ pred, const float* __restrict__ coord,
        const int* __restrict__ segment, const int* __restrict__ offset,
        unsigned* __restrict__ ws, float* __restrict__ out, int n, int nb) {
    __shared__ unsigned s_stats[32];
    __shared__ unsigned s_comb[32];
    __shared__ float    s_mu[8];
    __shared__ float    s_part[THREADS / 64];
    const int tid = threadIdx.x;

    if (tid < 32) s_stats[tid] = ident_w(tid);
    if (blockIdx.x == 0 && tid == THREADS - 1) {      // zero acc + done (device-scope)
        atomicExch((unsigned long long*)(ws + 32), 0ull);
        atomicExch(&ws[34], 0u);
    }
    int roff[8];
    #pragma unroll
    for (int j = 0; j < 8; ++j) roff[j] = (j < nb) ? offset[j] : 0x7FFFFFFF;
    __syncthreads();

    const int chunk = (n + (int)gridDim.x - 1) / (int)gridDim.x;
    const int start = blockIdx.x * chunk;
    const int end   = min(n, start + chunk);

    float    zc[CACHE_K];          // register cache: z per thread-owned point (fast path only)
    unsigned segbits = 0u;         // bit k = segment label of point k       (fast path only)
    int  ba = 0, bb = 0;
    bool fast = false;

    if (start < end) {
        #pragma unroll
        for (int j = 0; j < 8; ++j) { ba += (start >= roff[j]); bb += ((end - 1) >= roff[j]); }
        // fast requires: single cloud AND a full tile (no bounds checks anywhere inside)
        fast = (ba == bb) && (end - start == CACHE_K * THREADS);
    }

    // ---------------- phase 1: stats over (z, segment) ----------------
    if (fast) {
        const int ibase = start + tid;
        int sv[CACHE_K];
        #pragma unroll
        for (int k = 0; k < CACHE_K; ++k) zc[k] = coord[3 * (ibase + k * THREADS) + 2];
        #pragma unroll
        for (int k = 0; k < CACHE_K; ++k) sv[k] = segment[ibase + k * THREADS];

        float lg = -INFINITY, lp = INFINITY, lmn = INFINITY, lmx = -INFINITY;
        #pragma unroll
        for (int k = 0; k < CACHE_K; ++k) {
            float z = zc[k];
            segbits |= (unsigned)(sv[k] & 1) << k;
            lmn = fminf(lmn, z); lmx = fmaxf(lmx, z);
            lg  = fmaxf(lg, (sv[k] == 0) ? z : -INFINITY);
            lp  = fminf(lp, (sv[k] != 0) ? z : INFINITY);
        }
        #pragma unroll
        for (int m = 32; m; m >>= 1) {
            lg  = fmaxf(lg,  __shfl_xor(lg,  m, 64));
            lp  = fminf(lp,  __shfl_xor(lp,  m, 64));
            lmn = fminf(lmn, __shfl_xor(lmn, m, 64));
            lmx = fmaxf(lmx, __shfl_xor(lmx, m, 64));
        }
        if ((tid & 63) == 0) FLUSH_LDS(ba, lg, lp, lmn, lmx);
    } else if (start < end) {
        // general path (boundary/tail blocks): stream, NO register caching
        float lg = -INFINITY, lp = INFINITY, lmn = INFINITY, lmx = -INFINITY;
        int curb = -1;
        for (int i = start + tid; i < end; i += THREADS) {
            float z = coord[3 * i + 2]; int s = segment[i], b;
            CNT_B(i, b);
            if (b != curb) {
                if (curb >= 0) FLUSH_LDS(curb, lg, lp, lmn, lmx);
                lg = -INFINITY; lp = INFINITY; lmn = INFINITY; lmx = -INFINITY;
                curb = b;
            }
            lmn = fminf(lmn, z); lmx = fmaxf(lmx, z);
            if (s == 0) lg = fmaxf(lg, z); else lp = fminf(lp, z);
        }
        if (curb >= 0) FLUSH_LDS(curb, lg, lp, lmn, lmx);
    }
    __syncthreads();
    if (tid < 32) SLOT(ws, blockIdx.x)[tid] = s_stats[tid];
    __threadfence();                 // make record visible device-wide before barrier
    cg::this_grid().sync();          // grid-wide barrier (256 blocks, 1/CU, co-resident)

    // ---------------- reduce the 256 per-block stat records ----------------
    if (tid < 32) s_comb[tid] = ident_w(tid);
    __syncthreads();
    {
        const int w = tid & 31, g = tid >> 5;          // 32 groups x 32 words
        unsigned v = ident_w(w);
        #pragma unroll
        for (int j = 0; j < NBLOCKS / 32; ++j) {
            unsigned u = SLOT((const unsigned*)ws, g * (NBLOCKS / 32) + j)[w];
            v = (w < 8 || w >= 24) ? max(v, u) : min(v, u);
        }
        if (w < 8 || w >= 24) atomicMax(&s_comb[w], v);
        else                  atomicMin(&s_comb[w], v);
    }
    __syncthreads();
    if (tid < 8) {
        unsigned ug = s_comb[tid], up = s_comb[8 + tid];
        float g = dec_f(ug), p = dec_f(up);
        if (ug == ENC_NEG_INF) g = dec_f(s_comb[16 + tid]);  // no ground -> z.min
        if (up == ENC_POS_INF) p = dec_f(s_comb[24 + tid]);  // no plant  -> z.max
        s_mu[tid] = g + (p - g) * 0.5f;
    }
    __syncthreads();

    // ---------------- phase 2: loss; fast path fetches only pred ----------------
    const float2* pred2 = (const float2*)pred;
    float lsum = 0.0f;
    if (fast) {
        const float mu = s_mu[ba];
        const int ibase = start + tid;
        #pragma unroll
        for (int k0 = 0; k0 < CACHE_K; k0 += 8) {   // groups of 8 bound VGPR pressure
            float2 pp[8];
            #pragma unroll
            for (int kk = 0; kk < 8; ++kk) pp[kk] = pred2[ibase + (k0 + kk) * THREADS];
            #pragma unroll
            for (int kk = 0; kk < 8; ++kk)
                lsum += point_loss(pp[kk].x, pp[kk].y,
                                   (int)((segbits >> (k0 + kk)) & 1u),
                                   zc[k0 + kk], mu);
        }
    } else if (start < end) {
        // general path: reload z/segment from global (matches old 2-kernel behavior)
        for (int i = start + tid; i < end; i += THREADS) {
            int b; CNT_B(i, b);
            float2 pp = pred2[i];
            lsum += point_loss(pp.x, pp.y, segment[i], coord[3 * i + 2], s_mu[b]);
        }
    }

    #pragma unroll
    for (int off = 32; off > 0; off >>= 1) lsum += __shfl_down(lsum, off, 64);
    if ((tid & 63) == 0) s_part[tid >> 6] = lsum;
    __syncthreads();
    if (tid == 0) {
        float t = 0.0f;
        #pragma unroll
        for (int wv = 0; wv < THREADS / 64; ++wv) t += s_part[wv];
        double* acc = (double*)(ws + 32);
        atomicAdd(acc, (double)t);
        __threadfence();
        unsigned c = atomicAdd(&ws[34], 1u);
        if (c == (unsigned)gridDim.x - 1u) {       // last block finalizes
            double v = atomicAdd(acc, 0.0);        // coherent read via atomic
            out[0] = (float)(v / (double)n);
        }
    }
}

extern "C" void kernel_launch(void* const* d_in, const int* in_sizes, int n_in,
                              void* d_out, int out_size, void* d_ws, size_t ws_size,
                              hipStream_t stream) {
    const float* pred    = (const float*)d_in[0];
    const float* coord   = (const float*)d_in[1];
    const int*   segment = (const int*)d_in[2];
    const int*   offset  = (const int*)d_in[3];
    int n  = in_sizes[2];
    int nb = in_sizes[3];
    unsigned* ws = (unsigned*)d_ws;
    float* out = (float*)d_out;

    void* args[] = { (void*)&pred, (void*)&coord, (void*)&segment, (void*)&offset,
                     (void*)&ws, (void*)&out, (void*)&n, (void*)&nb };
    hipLaunchCooperativeKernel((void*)k_fused, dim3(NBLOCKS), dim3(THREADS),
                               args, 0, stream);
}

// Round 3
// 172.559 us; speedup vs baseline: 1.3128x; 1.3128x over previous
//
#include <hip/hip_runtime.h>
#include <math.h>

#define THREADS 1024   // 16 waves/block, 1 block/CU at grid 256 (coop co-residency exact)
#define NBLOCKS 256
#define CACHE_K 16     // 4M points / (256*1024) = 16 points/thread, all cached in regs

// ---- monotone float <-> uint encoding (order-preserving) ----
__device__ __forceinline__ unsigned enc_f(float f) {
    unsigned b = __float_as_uint(f);
    return (b & 0x80000000u) ? ~b : (b | 0x80000000u);
}
__device__ __forceinline__ float dec_f(unsigned u) {
    unsigned b = (u & 0x80000000u) ? (u ^ 0x80000000u) : ~u;
    return __uint_as_float(b);
}
#define ENC_NEG_INF 0x007FFFFFu   // enc(-inf): identity for max
#define ENC_POS_INF 0xFF800000u   // enc(+inf): identity for min
// word w in a 32-word stat record: [0..7] gmax(max) [8..15] pmin(min) [16..23] zmin(min) [24..31] zmax(max)
__device__ __forceinline__ unsigned ident_w(int w) {
    return (w < 8 || w >= 24) ? ENC_NEG_INF : ENC_POS_INF;
}

// ws layout (unsigned*):
//   [32..33] double acc | [34] done-counter          (zeroed by block 0 at entry;
//                                                     ordered before use via flag[0] chain)
//   [64 + blk*32 + w]   per-block stat records       (agent-scope atomic stores)
//   [12288 + blk]       per-block arrival flags      (MAGIC after record published)
// Harness re-poisons the whole ws between iterations -> flags/acc never stale.
#define SLOT(base, blk) ((base) + 64 + (blk) * 32)
#define FLAG_BASE  12288
#define FLAG_MAGIC 0x9E3779B9u

#define CNT_B(ii, bdst) do { bdst = 0; \
    _Pragma("unroll") for (int j_ = 0; j_ < 8; ++j_) bdst += ((ii) >= roff[j_]); } while (0)

#define FLUSH_LDS(bb, g_, p_, mn_, mx_) do { \
    atomicMax(&s_stats[      (bb)], enc_f(g_));  \
    atomicMin(&s_stats[ 8  + (bb)], enc_f(p_));  \
    atomicMin(&s_stats[16  + (bb)], enc_f(mn_)); \
    atomicMax(&s_stats[24  + (bb)], enc_f(mx_)); } while (0)

__device__ __forceinline__ float point_loss(float p0, float p1, int s, float z, float mu) {
    float m   = fmaxf(p0, p1);
    float lse = m + logf(expf(p0 - m) + expf(p1 - m));
    float lpt = ((s == 0) ? p0 : p1) - lse;
    float pt  = expf(lpt);
    float om  = 1.0f - pt;
    float loss = -lpt * om * om;           // LOSS_WEIGHT=ALPHA=1, GAMMA=2
    float d  = z - mu;
    float cf = (z <= mu) ? 50.0f : 3.125f; // 1/(2*0.1^2), 1/(2*0.4^2)
    float w  = expf(-d * d * cf);
    if (z > mu && d > 0.8f) w = 0.1f;      // d > 2*0.4 -> MIN_VAL
    return loss * w;
}

// Fused single-pass kernel with a fully INLINE grid barrier (no cg::sync -> no OCKL
// call -> no ABI spill of the register cache; R1/R2 regression root cause).
// Phase 1: stats over (z, seg), cached in regs on full uniform tiles.
// Barrier: per-block record + flag, agent-scope atomics (sc1, cross-XCD coherent).
// Phase 2: loss; fast tiles fetch ONLY pred from HBM (saves 64 MB vs 2-kernel).
__global__ __launch_bounds__(THREADS, 4) void k_fused(
        const float* __restrict__ pred, const float* __restrict__ coord,
        const int* __restrict__ segment, const int* __restrict__ offset,
        unsigned* __restrict__ ws, float* __restrict__ out, int n, int nb) {
    __shared__ unsigned s_stats[32];
    __shared__ unsigned s_comb[32];
    __shared__ float    s_mu[8];
    __shared__ float    s_part[THREADS / 64];
    const int tid = threadIdx.x;

    if (tid < 32) s_stats[tid] = ident_w(tid);
    if (blockIdx.x == 0 && tid == THREADS - 1) {      // zero acc + done (agent scope)
        __hip_atomic_store((unsigned long long*)(ws + 32), 0ull,
                           __ATOMIC_RELAXED, __HIP_MEMORY_SCOPE_AGENT);
        __hip_atomic_store(&ws[34], 0u, __ATOMIC_RELAXED, __HIP_MEMORY_SCOPE_AGENT);
    }
    int roff[8];
    #pragma unroll
    for (int j = 0; j < 8; ++j) roff[j] = (j < nb) ? offset[j] : 0x7FFFFFFF;
    __syncthreads();

    const int chunk = (n + (int)gridDim.x - 1) / (int)gridDim.x;
    const int start = blockIdx.x * chunk;
    const int end   = min(n, start + chunk);

    float    zc[CACHE_K];          // register cache: z per thread-owned point (fast path only)
    unsigned segbits = 0u;         // bit k = segment label of point k       (fast path only)
    int  ba = 0, bb = 0;
    bool fast = false;

    if (start < end) {
        #pragma unroll
        for (int j = 0; j < 8; ++j) { ba += (start >= roff[j]); bb += ((end - 1) >= roff[j]); }
        // fast requires: single cloud AND a full tile (no bounds checks inside)
        fast = (ba == bb) && (end - start == CACHE_K * THREADS);
    }

    // ---------------- phase 1: stats over (z, segment) ----------------
    if (fast) {
        const int ibase = start + tid;
        int sv[CACHE_K];
        #pragma unroll
        for (int k = 0; k < CACHE_K; ++k) zc[k] = coord[3 * (ibase + k * THREADS) + 2];
        #pragma unroll
        for (int k = 0; k < CACHE_K; ++k) sv[k] = segment[ibase + k * THREADS];

        float lg = -INFINITY, lp = INFINITY, lmn = INFINITY, lmx = -INFINITY;
        #pragma unroll
        for (int k = 0; k < CACHE_K; ++k) {
            float z = zc[k];
            segbits |= (unsigned)(sv[k] & 1) << k;
            lmn = fminf(lmn, z); lmx = fmaxf(lmx, z);
            lg  = fmaxf(lg, (sv[k] == 0) ? z : -INFINITY);
            lp  = fminf(lp, (sv[k] != 0) ? z : INFINITY);
        }
        #pragma unroll
        for (int m = 32; m; m >>= 1) {
            lg  = fmaxf(lg,  __shfl_xor(lg,  m, 64));
            lp  = fminf(lp,  __shfl_xor(lp,  m, 64));
            lmn = fminf(lmn, __shfl_xor(lmn, m, 64));
            lmx = fmaxf(lmx, __shfl_xor(lmx, m, 64));
        }
        if ((tid & 63) == 0) FLUSH_LDS(ba, lg, lp, lmn, lmx);
    } else if (start < end) {
        // general path (boundary/partial blocks): stream, NO register caching
        float lg = -INFINITY, lp = INFINITY, lmn = INFINITY, lmx = -INFINITY;
        int curb = -1;
        for (int i = start + tid; i < end; i += THREADS) {
            float z = coord[3 * i + 2]; int s = segment[i], b;
            CNT_B(i, b);
            if (b != curb) {
                if (curb >= 0) FLUSH_LDS(curb, lg, lp, lmn, lmx);
                lg = -INFINITY; lp = INFINITY; lmn = INFINITY; lmx = -INFINITY;
                curb = b;
            }
            lmn = fminf(lmn, z); lmx = fmaxf(lmx, z);
            if (s == 0) lg = fmaxf(lg, z); else lp = fminf(lp, z);
        }
        if (curb >= 0) FLUSH_LDS(curb, lg, lp, lmn, lmx);
    }
    __syncthreads();

    // ---------------- inline grid barrier: publish record, then flag ----------------
    if (tid < 32)
        __hip_atomic_store(&SLOT(ws, blockIdx.x)[tid], s_stats[tid],
                           __ATOMIC_RELAXED, __HIP_MEMORY_SCOPE_AGENT);
    __syncthreads();                                  // record fully issued by this block
    if (tid == 0) {
        __threadfence();                              // order record (and block0 init) first
        __hip_atomic_store(&ws[FLAG_BASE + blockIdx.x], FLAG_MAGIC,
                           __ATOMIC_RELEASE, __HIP_MEMORY_SCOPE_AGENT);
    }
    if (tid < NBLOCKS) {                              // one flag per thread, inline spin
        while (__hip_atomic_load(&ws[FLAG_BASE + tid],
                                 __ATOMIC_ACQUIRE, __HIP_MEMORY_SCOPE_AGENT) != FLAG_MAGIC)
            __builtin_amdgcn_s_sleep(1);
    }
    __syncthreads();                                  // all 256 records visible

    // ---------------- reduce the 256 per-block stat records ----------------
    if (tid < 32) s_comb[tid] = ident_w(tid);
    __syncthreads();
    {
        const int w = tid & 31, g = tid >> 5;          // 32 groups x 32 words
        unsigned v = ident_w(w);
        #pragma unroll
        for (int j = 0; j < NBLOCKS / 32; ++j) {
            unsigned u = __hip_atomic_load(&SLOT((const unsigned*)ws, g * (NBLOCKS / 32) + j)[w],
                                           __ATOMIC_RELAXED, __HIP_MEMORY_SCOPE_AGENT);
            v = (w < 8 || w >= 24) ? max(v, u) : min(v, u);
        }
        if (w < 8 || w >= 24) atomicMax(&s_comb[w], v);
        else                  atomicMin(&s_comb[w], v);
    }
    __syncthreads();
    if (tid < 8) {
        unsigned ug = s_comb[tid], up = s_comb[8 + tid];
        float g = dec_f(ug), p = dec_f(up);
        if (ug == ENC_NEG_INF) g = dec_f(s_comb[16 + tid]);  // no ground -> z.min
        if (up == ENC_POS_INF) p = dec_f(s_comb[24 + tid]);  // no plant  -> z.max
        s_mu[tid] = g + (p - g) * 0.5f;
    }
    __syncthreads();

    // ---------------- phase 2: loss; fast path fetches only pred ----------------
    const float2* pred2 = (const float2*)pred;
    float lsum = 0.0f;
    if (fast) {
        const float mu = s_mu[ba];
        const int ibase = start + tid;
        #pragma unroll
        for (int k0 = 0; k0 < CACHE_K; k0 += 8) {   // groups of 8 bound VGPR pressure
            float2 pp[8];
            #pragma unroll
            for (int kk = 0; kk < 8; ++kk) pp[kk] = pred2[ibase + (k0 + kk) * THREADS];
            #pragma unroll
            for (int kk = 0; kk < 8; ++kk)
                lsum += point_loss(pp[kk].x, pp[kk].y,
                                   (int)((segbits >> (k0 + kk)) & 1u),
                                   zc[k0 + kk], mu);
        }
    } else if (start < end) {
        // general path: reload z/segment from global (matches old 2-kernel behavior)
        for (int i = start + tid; i < end; i += THREADS) {
            int b; CNT_B(i, b);
            float2 pp = pred2[i];
            lsum += point_loss(pp.x, pp.y, segment[i], coord[3 * i + 2], s_mu[b]);
        }
    }

    #pragma unroll
    for (int off = 32; off > 0; off >>= 1) lsum += __shfl_down(lsum, off, 64);
    if ((tid & 63) == 0) s_part[tid >> 6] = lsum;
    __syncthreads();
    if (tid == 0) {
        float t = 0.0f;
        #pragma unroll
        for (int wv = 0; wv < THREADS / 64; ++wv) t += s_part[wv];
        double* acc = (double*)(ws + 32);
        atomicAdd(acc, (double)t);
        __threadfence();
        unsigned c = atomicAdd(&ws[34], 1u);
        if (c == (unsigned)gridDim.x - 1u) {       // last block finalizes
            double v = atomicAdd(acc, 0.0);        // coherent read via atomic
            out[0] = (float)(v / (double)n);
        }
    }
}

extern "C" void kernel_launch(void* const* d_in, const int* in_sizes, int n_in,
                              void* d_out, int out_size, void* d_ws, size_t ws_size,
                              hipStream_t stream) {
    const float* pred    = (const float*)d_in[0];
    const float* coord   = (const float*)d_in[1];
    const int*   segment = (const int*)d_in[2];
    const int*   offset  = (const int*)d_in[3];
    int n  = in_sizes[2];
    int nb = in_sizes[3];
    unsigned* ws = (unsigned*)d_ws;
    float* out = (float*)d_out;

    void* args[] = { (void*)&pred, (void*)&coord, (void*)&segment, (void*)&offset,
                     (void*)&ws, (void*)&out, (void*)&n, (void*)&nb };
    // cooperative launch kept ONLY for the co-residency guarantee (spin safety);
    // the barrier itself is inline (no cg::sync, no OCKL call).
    hipLaunchCooperativeKernel((void*)k_fused, dim3(NBLOCKS), dim3(THREADS),
                               args, 0, stream);
}